// Round 10
// baseline (370.946 us; speedup 1.0000x reference)
//
#include <hip/hip_runtime.h>
#include <math.h>

#define NPTS 4096
#define NBATCH 8
#define G 48
#define NC (G * G * G)          // 110592 cells per batch
#define H 0.25f
#define GINV 4.0f               // 1/H
#define GORG 6.0f               // grid covers [-6, 6)

// ws layout (float offsets):
#define WS_CENT 0                          // 128: centroid partials [b][quad][4]
#define WS_COEF 128                        // 768: A0,A1,A2,vd,vl,beff each [128]
#define WS_CNT  1024                       // 8*NC ints: cell counts (zeroed each call)
#define WS_OFF  (1024 + NC * NBATCH)       // 8*NC ints: prefix; post-scatter = cell ends
#define WS_SRT  (WS_OFF + NC * NBATCH)     // 8*4096 float4: cell-sorted (x,y,z,orig_idx)
#define WS_DENS (WS_SRT + NPTS * NBATCH * 4) // 8*4096 floats: density per original index

__device__ __forceinline__ int cellco(float v) {
    int c = (int)floorf((v + GORG) * GINV);
    return min(max(c, 0), G - 1);
}

// 3-op sorted-triple insert via med3 (rank-k insert identity). Keeps t0<=t1<=t2.
#define INS3(t0, t1, t2, v)                                   \
    {                                                         \
        float n0 = fminf(t0, (v));                            \
        float n1 = __builtin_amdgcn_fmed3f(t0, t1, (v));      \
        float n2 = __builtin_amdgcn_fmed3f(t1, t2, (v));      \
        t0 = n0; t1 = n1; t2 = n2;                            \
    }

// Zero the cell-count region. 884736 floats = 221184 float4 -> 864 blocks x 256.
__launch_bounds__(256)
__global__ void zero_kernel(float* __restrict__ ws) {
    ((float4*)(ws + WS_CNT))[blockIdx.x * 256 + threadIdx.x] =
        make_float4(0.f, 0.f, 0.f, 0.f);
}

// 32 blocks x 1024: thread = one point. Cell count (atomic) + deterministic
// centroid partial per block (4 blocks per batch, fixed slots).
__launch_bounds__(1024)
__global__ void count_kernel(const float* __restrict__ pts, float* __restrict__ ws) {
    int gid = blockIdx.x * 1024 + threadIdx.x;
    int b = gid >> 12;
    const float* P = pts + (size_t)gid * 3;
    float px = P[0], py = P[1], pz = P[2];
    int cell = (cellco(pz) * G + cellco(py)) * G + cellco(px);
    atomicAdd((int*)ws + WS_CNT + b * NC + cell, 1);

    float sx = px, sy = py, sz = pz;
    #pragma unroll
    for (int m = 1; m < 64; m <<= 1) {
        sx += __shfl_xor(sx, m);
        sy += __shfl_xor(sy, m);
        sz += __shfl_xor(sz, m);
    }
    __shared__ float rx[16], ry[16], rz[16];
    int w = threadIdx.x >> 6, lane = threadIdx.x & 63;
    if (lane == 0) { rx[w] = sx; ry[w] = sy; rz[w] = sz; }
    __syncthreads();
    if (threadIdx.x == 0) {
        float ax = 0.f, ay = 0.f, az = 0.f;
        for (int i = 0; i < 16; ++i) { ax += rx[i]; ay += ry[i]; az += rz[i]; }
        ws[WS_CENT + blockIdx.x * 4 + 0] = ax;
        ws[WS_CENT + blockIdx.x * 4 + 1] = ay;
        ws[WS_CENT + blockIdx.x * 4 + 2] = az;
    }
}

#define PER (NC / 1024)   // 108 cells per thread

// blocks 0..7: per-batch exclusive prefix over NC cell counts; block 8: coeff fold.
__launch_bounds__(1024)
__global__ void prefix_kernel(const float* __restrict__ W_rel, const float* __restrict__ b_rel,
                              const float* __restrict__ W_dist, const float* __restrict__ b_dist,
                              const float* __restrict__ W_dens, const float* __restrict__ b_dens,
                              const float* __restrict__ W_out, const float* __restrict__ b_out,
                              float* __restrict__ ws) {
    if (blockIdx.x == NBATCH) {
        if (threadIdx.x < 128) {
            int o = threadIdx.x;
            float a0 = 0.f, a1 = 0.f, a2 = 0.f, vd = 0.f, vl = 0.f, be = b_out[o];
            for (int j = 0; j < 42; ++j) {
                float w0 = W_out[j * 128 + o];
                float w1 = W_out[(42 + j) * 128 + o];
                float w2 = W_out[(84 + j) * 128 + o];
                a0 = fmaf(W_rel[j],      w0, a0);
                a1 = fmaf(W_rel[42 + j], w0, a1);
                a2 = fmaf(W_rel[84 + j], w0, a2);
                vd = fmaf(W_dist[j],     w1, vd);
                vl = fmaf(W_dens[j],     w2, vl);
                be = fmaf(b_rel[j],  w0, be);
                be = fmaf(b_dist[j], w1, be);
                be = fmaf(b_dens[j], w2, be);
            }
            float* C = ws + WS_COEF;
            C[0 * 128 + o] = a0; C[1 * 128 + o] = a1; C[2 * 128 + o] = a2;
            C[3 * 128 + o] = vd; C[4 * 128 + o] = vl; C[5 * 128 + o] = be;
        }
        return;
    }
    int b = blockIdx.x;
    const int* cnt = (const int*)ws + WS_CNT + b * NC;
    int* off = (int*)ws + WS_OFF + b * NC;
    int t = threadIdx.x;
    int base = t * PER;
    int s = 0;
    for (int i = 0; i < PER; ++i) s += cnt[base + i];
    // block exclusive scan of per-thread sums
    int lane = t & 63, w = t >> 6;
    int v = s;
    #pragma unroll
    for (int d = 1; d < 64; d <<= 1) {
        int u = __shfl_up(v, d);
        if (lane >= d) v += u;
    }
    __shared__ int wsum[16];
    if (lane == 63) wsum[w] = v;
    __syncthreads();
    if (w == 0 && lane < 16) {
        int x = wsum[lane];
        #pragma unroll
        for (int d = 1; d < 16; d <<= 1) {
            int u = __shfl_up(x, d);
            if (lane >= d) x += u;
        }
        wsum[lane] = x;
    }
    __syncthreads();
    int run = v - s + (w ? wsum[w - 1] : 0);
    for (int i = 0; i < PER; ++i) { off[base + i] = run; run += cnt[base + i]; }
}

// 32 blocks x 1024: scatter points into cell-sorted order. atomicAdd on off[]
// doubles as the cursor; afterwards off[c] == pristine off[c+1] (cell end).
__launch_bounds__(1024)
__global__ void scatter_kernel(const float* __restrict__ pts, float* __restrict__ ws) {
    int gid = blockIdx.x * 1024 + threadIdx.x;
    int b = gid >> 12, n = gid & 4095;
    const float* P = pts + (size_t)gid * 3;
    float px = P[0], py = P[1], pz = P[2];
    int cell = (cellco(pz) * G + cellco(py)) * G + cellco(px);
    int slot = atomicAdd((int*)ws + WS_OFF + b * NC + cell, 1);
    ((float4*)(ws + WS_SRT))[b * NPTS + slot] = make_float4(px, py, pz, __int_as_float(n));
}

// 256 blocks x 128: thread = one sorted point (spatially coherent waves).
// Ring search: scan cell block radius r; any point outside the block is > r*H
// away (margin >= r*H in some axis), so t2 <= (r*H)^2 proves exactness.
// Cells are x-contiguous -> one offset pair per x-row. Expansion rescans
// from scratch (no double-insert). E[c] = cell end; start = E[c-1] (or 0).
__launch_bounds__(128)
__global__ void knn_kernel(float* __restrict__ ws) {
    int gid = blockIdx.x * 128 + threadIdx.x;
    int b = gid >> 12, s = gid & 4095;
    const float4* S = (const float4*)(ws + WS_SRT) + (size_t)b * NPTS;
    const int* E = (const int*)ws + WS_OFF + b * NC;
    float4 p = S[s];
    float px = p.x, py = p.y, pz = p.z;
    int cx = cellco(px), cy = cellco(py), cz = cellco(pz);
    float t0, t1, t2;
    for (int r = 1;; ++r) {
        t0 = INFINITY; t1 = INFINITY; t2 = INFINITY;
        int zlo = max(cz - r, 0), zhi = min(cz + r, G - 1);
        int ylo = max(cy - r, 0), yhi = min(cy + r, G - 1);
        int x0 = max(cx - r, 0), x1 = min(cx + r, G - 1);
        for (int z = zlo; z <= zhi; ++z) {
            for (int y = ylo; y <= yhi; ++y) {
                int rowc = (z * G + y) * G;
                int ia = rowc + x0;
                int a = ia ? E[ia - 1] : 0;
                int e = E[rowc + x1];
                for (int m = a; m < e; ++m) {
                    float4 c = S[m];
                    float dx = px - c.x, dy = py - c.y, dz2 = pz - c.z;
                    float d2 = fmaf(dx, dx, fmaf(dy, dy, dz2 * dz2));
                    d2 = (m == s) ? INFINITY : d2;   // exclude self
                    INS3(t0, t1, t2, d2);
                }
            }
        }
        float cov = (float)r * H;
        if (t2 <= cov * cov || r >= G) break;
    }
    float ld = (sqrtf(fmaxf(t0, 1e-12f)) + sqrtf(fmaxf(t1, 1e-12f)) +
                sqrtf(fmaxf(t2, 1e-12f))) * (1.0f / 3.0f);
    ws[WS_DENS + b * NPTS + __float_as_int(p.w)] = ld;
}

// 4096 blocks x 256: 8 rows x 32 float4-cols, fully coalesced 512B row stores.
__launch_bounds__(256)
__global__ void output_kernel(const float* __restrict__ pts, const float* __restrict__ ws,
                              float* __restrict__ out) {
    int row = blockIdx.x * 8 + (threadIdx.x >> 5);   // global (b*4096+n)
    int b = row >> 12;
    int q = threadIdx.x & 31;

    const float inv = 1.0f / (float)NPTS;
    int cb = WS_CENT + b * 16;
    float cx = (ws[cb + 0] + ws[cb + 4] + ws[cb + 8] + ws[cb + 12]) * inv;
    float cy = (ws[cb + 1] + ws[cb + 5] + ws[cb + 9] + ws[cb + 13]) * inv;
    float cz = (ws[cb + 2] + ws[cb + 6] + ws[cb + 10] + ws[cb + 14]) * inv;

    const float* P = pts + (size_t)row * 3;
    float rx = P[0] - cx, ry = P[1] - cy, rz = P[2] - cz;
    float cd = sqrtf(fmaf(rx, rx, fmaf(ry, ry, rz * rz)));
    float ld = ws[WS_DENS + row];

    const float4* Cg = (const float4*)(ws + WS_COEF);  // 6 rows x 32 float4
    float4 A0 = Cg[0 * 32 + q];
    float4 A1 = Cg[1 * 32 + q];
    float4 A2 = Cg[2 * 32 + q];
    float4 VD = Cg[3 * 32 + q];
    float4 VL = Cg[4 * 32 + q];
    float4 BE = Cg[5 * 32 + q];
    float4 rv;
    rv.x = fmaf(rx, A0.x, fmaf(ry, A1.x, fmaf(rz, A2.x, fmaf(cd, VD.x, fmaf(ld, VL.x, BE.x)))));
    rv.y = fmaf(rx, A0.y, fmaf(ry, A1.y, fmaf(rz, A2.y, fmaf(cd, VD.y, fmaf(ld, VL.y, BE.y)))));
    rv.z = fmaf(rx, A0.z, fmaf(ry, A1.z, fmaf(rz, A2.z, fmaf(cd, VD.z, fmaf(ld, VL.z, BE.z)))));
    rv.w = fmaf(rx, A0.w, fmaf(ry, A1.w, fmaf(rz, A2.w, fmaf(cd, VD.w, fmaf(ld, VL.w, BE.w)))));
    ((float4*)(out + (size_t)row * 128))[q] = rv;
}

extern "C" void kernel_launch(void* const* d_in, const int* in_sizes, int n_in,
                              void* d_out, int out_size, void* d_ws, size_t ws_size,
                              hipStream_t stream) {
    const float* pts    = (const float*)d_in[0];
    const float* W_rel  = (const float*)d_in[1];
    const float* b_rel  = (const float*)d_in[2];
    const float* W_dist = (const float*)d_in[3];
    const float* b_dist = (const float*)d_in[4];
    const float* W_dens = (const float*)d_in[5];
    const float* b_dens = (const float*)d_in[6];
    const float* W_out  = (const float*)d_in[7];
    const float* b_out  = (const float*)d_in[8];
    float* out = (float*)d_out;
    float* ws  = (float*)d_ws;

    hipLaunchKernelGGL(zero_kernel, dim3(NC * NBATCH / 1024), dim3(256), 0, stream, ws);
    hipLaunchKernelGGL(count_kernel, dim3(32), dim3(1024), 0, stream, pts, ws);
    hipLaunchKernelGGL(prefix_kernel, dim3(NBATCH + 1), dim3(1024), 0, stream,
                       W_rel, b_rel, W_dist, b_dist, W_dens, b_dens, W_out, b_out, ws);
    hipLaunchKernelGGL(scatter_kernel, dim3(32), dim3(1024), 0, stream, pts, ws);
    hipLaunchKernelGGL(knn_kernel, dim3(256), dim3(128), 0, stream, ws);
    hipLaunchKernelGGL(output_kernel, dim3(4096), dim3(256), 0, stream, pts, ws, out);
}

// Round 11
// 201.537 us; speedup vs baseline: 1.8406x; 1.8406x over previous
//
#include <hip/hip_runtime.h>
#include <math.h>

#define NPTS 4096
#define NBATCH 8
#define G 32
#define NC (G * G * G)          // 32768 cells per batch
#define H 0.375f
#define GINV (1.0f / 0.375f)
#define GORG 6.0f               // grid covers [-6, 6)

// ws layout (float offsets):
#define WS_CENT 0                            // 128: centroid partials [b][quad][4]
#define WS_COEF 128                          // 768: A0,A1,A2,vd,vl,beff each [128]
#define WS_CNT  1024                         // 8*NC ints: cell counts (memset to 0)
#define WS_OFF  (1024 + NC * NBATCH)         // 8*NC ints: prefix; post-scatter = cell ends
#define WS_SRT  (WS_OFF + NC * NBATCH)       // 8*4096 float4: cell-sorted (x,y,z,orig_idx)
#define WS_DENS (WS_SRT + NPTS * NBATCH * 4) // 8*4096 floats: density per original index

__device__ __forceinline__ int cellco(float v) {
    int c = (int)floorf((v + GORG) * GINV);
    return min(max(c, 0), G - 1);
}

// 3-op sorted-triple insert via med3 (rank-k insert identity). Keeps t0<=t1<=t2.
#define INS3(t0, t1, t2, v)                                   \
    {                                                         \
        float n0 = fminf(t0, (v));                            \
        float n1 = __builtin_amdgcn_fmed3f(t0, t1, (v));      \
        float n2 = __builtin_amdgcn_fmed3f(t1, t2, (v));      \
        t0 = n0; t1 = n1; t2 = n2;                            \
    }

// Merge partner's sorted triple (7 min/max) via xor-butterfly step.
#define MERGE3(t0, t1, t2, m)                                 \
    {                                                         \
        float b0 = __shfl_xor(t0, m);                         \
        float b1 = __shfl_xor(t1, m);                         \
        float b2 = __shfl_xor(t2, m);                         \
        float X = fmaxf(t0, b0);                              \
        t0 = fminf(t0, b0);                                   \
        float Y = fminf(t1, b1);                              \
        float Z = fmaxf(X, Y);                                \
        t1 = fminf(X, Y);                                     \
        t2 = fminf(Z, fminf(t2, b2));                         \
    }

// 32 blocks x 1024: thread = one point. Cell count (atomic) + deterministic
// centroid partial per block (4 blocks per batch, fixed slots).
__launch_bounds__(1024)
__global__ void count_kernel(const float* __restrict__ pts, float* __restrict__ ws) {
    int gid = blockIdx.x * 1024 + threadIdx.x;
    int b = gid >> 12;
    const float* P = pts + (size_t)gid * 3;
    float px = P[0], py = P[1], pz = P[2];
    int cell = (cellco(pz) * G + cellco(py)) * G + cellco(px);
    atomicAdd((int*)ws + WS_CNT + b * NC + cell, 1);

    float sx = px, sy = py, sz = pz;
    #pragma unroll
    for (int m = 1; m < 64; m <<= 1) {
        sx += __shfl_xor(sx, m);
        sy += __shfl_xor(sy, m);
        sz += __shfl_xor(sz, m);
    }
    __shared__ float rx[16], ry[16], rz[16];
    int w = threadIdx.x >> 6, lane = threadIdx.x & 63;
    if (lane == 0) { rx[w] = sx; ry[w] = sy; rz[w] = sz; }
    __syncthreads();
    if (threadIdx.x == 0) {
        float ax = 0.f, ay = 0.f, az = 0.f;
        for (int i = 0; i < 16; ++i) { ax += rx[i]; ay += ry[i]; az += rz[i]; }
        ws[WS_CENT + blockIdx.x * 4 + 0] = ax;
        ws[WS_CENT + blockIdx.x * 4 + 1] = ay;
        ws[WS_CENT + blockIdx.x * 4 + 2] = az;
    }
}

// blocks 0..7: per-batch exclusive prefix over NC cells (32/thread, int4 x8);
// block 8: coeff fold.
__launch_bounds__(1024)
__global__ void prefix_kernel(const float* __restrict__ W_rel, const float* __restrict__ b_rel,
                              const float* __restrict__ W_dist, const float* __restrict__ b_dist,
                              const float* __restrict__ W_dens, const float* __restrict__ b_dens,
                              const float* __restrict__ W_out, const float* __restrict__ b_out,
                              float* __restrict__ ws) {
    if (blockIdx.x == NBATCH) {
        if (threadIdx.x < 128) {
            int o = threadIdx.x;
            float a0 = 0.f, a1 = 0.f, a2 = 0.f, vd = 0.f, vl = 0.f, be = b_out[o];
            for (int j = 0; j < 42; ++j) {
                float w0 = W_out[j * 128 + o];
                float w1 = W_out[(42 + j) * 128 + o];
                float w2 = W_out[(84 + j) * 128 + o];
                a0 = fmaf(W_rel[j],      w0, a0);
                a1 = fmaf(W_rel[42 + j], w0, a1);
                a2 = fmaf(W_rel[84 + j], w0, a2);
                vd = fmaf(W_dist[j],     w1, vd);
                vl = fmaf(W_dens[j],     w2, vl);
                be = fmaf(b_rel[j],  w0, be);
                be = fmaf(b_dist[j], w1, be);
                be = fmaf(b_dens[j], w2, be);
            }
            float* C = ws + WS_COEF;
            C[0 * 128 + o] = a0; C[1 * 128 + o] = a1; C[2 * 128 + o] = a2;
            C[3 * 128 + o] = vd; C[4 * 128 + o] = vl; C[5 * 128 + o] = be;
        }
        return;
    }
    int b = blockIdx.x;
    const int4* c4 = (const int4*)((const int*)ws + WS_CNT + b * NC);
    int4* o4 = (int4*)((int*)ws + WS_OFF + b * NC);
    int t = threadIdx.x;
    int4 v0 = c4[t * 8 + 0], v1 = c4[t * 8 + 1], v2 = c4[t * 8 + 2], v3 = c4[t * 8 + 3];
    int4 v4 = c4[t * 8 + 4], v5 = c4[t * 8 + 5], v6 = c4[t * 8 + 6], v7 = c4[t * 8 + 7];
    int s = v0.x + v0.y + v0.z + v0.w + v1.x + v1.y + v1.z + v1.w
          + v2.x + v2.y + v2.z + v2.w + v3.x + v3.y + v3.z + v3.w
          + v4.x + v4.y + v4.z + v4.w + v5.x + v5.y + v5.z + v5.w
          + v6.x + v6.y + v6.z + v6.w + v7.x + v7.y + v7.z + v7.w;
    int lane = t & 63, w = t >> 6;
    int v = s;
    #pragma unroll
    for (int d = 1; d < 64; d <<= 1) {
        int u = __shfl_up(v, d);
        if (lane >= d) v += u;
    }
    __shared__ int wsum[16];
    if (lane == 63) wsum[w] = v;
    __syncthreads();
    if (w == 0 && lane < 16) {
        int x = wsum[lane];
        #pragma unroll
        for (int d = 1; d < 16; d <<= 1) {
            int u = __shfl_up(x, d);
            if (lane >= d) x += u;
        }
        wsum[lane] = x;
    }
    __syncthreads();
    int run = v - s + (w ? wsum[w - 1] : 0);
    #define EMIT(vv, i)                                        \
        { int4 o; o.x = run; run += vv.x; o.y = run; run += vv.y; \
          o.z = run; run += vv.z; o.w = run; run += vv.w;         \
          o4[t * 8 + i] = o; }
    EMIT(v0, 0) EMIT(v1, 1) EMIT(v2, 2) EMIT(v3, 3)
    EMIT(v4, 4) EMIT(v5, 5) EMIT(v6, 6) EMIT(v7, 7)
    #undef EMIT
}

// 32 blocks x 1024: scatter points into cell-sorted order. atomicAdd on off[]
// doubles as the cursor; afterwards off[c] == pristine off[c+1] (cell end).
__launch_bounds__(1024)
__global__ void scatter_kernel(const float* __restrict__ pts, float* __restrict__ ws) {
    int gid = blockIdx.x * 1024 + threadIdx.x;
    int b = gid >> 12, n = gid & 4095;
    const float* P = pts + (size_t)gid * 3;
    float px = P[0], py = P[1], pz = P[2];
    int cell = (cellco(pz) * G + cellco(py)) * G + cellco(px);
    int slot = atomicAdd((int*)ws + WS_OFF + b * NC + cell, 1);
    ((float4*)(ws + WS_SRT))[b * NPTS + slot] = make_float4(px, py, pz, __int_as_float(n));
}

// 1024 blocks x 256: 8 LANES PER QUERY (32 queries/block, sorted order ->
// spatially coherent). At radius r the (z,y) rows of the cell block are
// round-robin'd across the 8 lanes; E-loads/S-gathers of the 8 lanes overlap.
// Triples merged via 3-step xor butterfly (masks 1,2,4 stay in-group); the
// rescan decision is then uniform across the group. Exactness: any point
// outside the radius-r block differs by >= r*H in some coordinate, so
// t2 <= (r*H)^2 proves the top-3 is final. Expansion rescans from scratch.
__launch_bounds__(256)
__global__ void knn_kernel(float* __restrict__ ws) {
    int tid = threadIdx.x;
    int sub = tid & 7;                    // lane within query-group
    int qid = blockIdx.x * 32 + (tid >> 3);
    int b = qid >> 12, s = qid & 4095;
    const float4* S = (const float4*)(ws + WS_SRT) + (size_t)b * NPTS;
    const int* E = (const int*)ws + WS_OFF + b * NC;
    float4 p = S[s];
    float px = p.x, py = p.y, pz = p.z;
    int cx = cellco(px), cy = cellco(py), cz = cellco(pz);
    float t0, t1, t2;
    for (int r = 1;; ++r) {
        t0 = INFINITY; t1 = INFINITY; t2 = INFINITY;
        int zlo = max(cz - r, 0), zhi = min(cz + r, G - 1);
        int ylo = max(cy - r, 0), yhi = min(cy + r, G - 1);
        int x0 = max(cx - r, 0), x1 = min(cx + r, G - 1);
        int c = 0;
        for (int z = zlo; z <= zhi; ++z) {
            int zg = z * G;
            for (int y = ylo; y <= yhi; ++y) {
                if ((c++ & 7) == sub) {
                    int rowc = (zg + y) * G;
                    int ia = rowc + x0;
                    int a = ia ? E[ia - 1] : 0;
                    int e = E[rowc + x1];
                    for (int m = a; m < e; ++m) {
                        float4 cd4 = S[m];
                        float dx = px - cd4.x, dy = py - cd4.y, dz = pz - cd4.z;
                        float d2 = fmaf(dx, dx, fmaf(dy, dy, dz * dz));
                        d2 = (m == s) ? INFINITY : d2;   // exclude self
                        INS3(t0, t1, t2, d2);
                    }
                }
            }
        }
        MERGE3(t0, t1, t2, 1);
        MERGE3(t0, t1, t2, 2);
        MERGE3(t0, t1, t2, 4);
        float cov = (float)r * H;
        if (t2 <= cov * cov || r >= G) break;
    }
    if (sub == 0) {
        float ld = (sqrtf(fmaxf(t0, 1e-12f)) + sqrtf(fmaxf(t1, 1e-12f)) +
                    sqrtf(fmaxf(t2, 1e-12f))) * (1.0f / 3.0f);
        ws[WS_DENS + b * NPTS + __float_as_int(p.w)] = ld;
    }
}

// 4096 blocks x 256: 8 rows x 32 float4-cols, fully coalesced 512B row stores.
__launch_bounds__(256)
__global__ void output_kernel(const float* __restrict__ pts, const float* __restrict__ ws,
                              float* __restrict__ out) {
    int row = blockIdx.x * 8 + (threadIdx.x >> 5);   // global (b*4096+n)
    int b = row >> 12;
    int q = threadIdx.x & 31;

    const float inv = 1.0f / (float)NPTS;
    int cb = WS_CENT + b * 16;
    float cx = (ws[cb + 0] + ws[cb + 4] + ws[cb + 8] + ws[cb + 12]) * inv;
    float cy = (ws[cb + 1] + ws[cb + 5] + ws[cb + 9] + ws[cb + 13]) * inv;
    float cz = (ws[cb + 2] + ws[cb + 6] + ws[cb + 10] + ws[cb + 14]) * inv;

    const float* P = pts + (size_t)row * 3;
    float rx = P[0] - cx, ry = P[1] - cy, rz = P[2] - cz;
    float cd = sqrtf(fmaf(rx, rx, fmaf(ry, ry, rz * rz)));
    float ld = ws[WS_DENS + row];

    const float4* Cg = (const float4*)(ws + WS_COEF);  // 6 rows x 32 float4
    float4 A0 = Cg[0 * 32 + q];
    float4 A1 = Cg[1 * 32 + q];
    float4 A2 = Cg[2 * 32 + q];
    float4 VD = Cg[3 * 32 + q];
    float4 VL = Cg[4 * 32 + q];
    float4 BE = Cg[5 * 32 + q];
    float4 rv;
    rv.x = fmaf(rx, A0.x, fmaf(ry, A1.x, fmaf(rz, A2.x, fmaf(cd, VD.x, fmaf(ld, VL.x, BE.x)))));
    rv.y = fmaf(rx, A0.y, fmaf(ry, A1.y, fmaf(rz, A2.y, fmaf(cd, VD.y, fmaf(ld, VL.y, BE.y)))));
    rv.z = fmaf(rx, A0.z, fmaf(ry, A1.z, fmaf(rz, A2.z, fmaf(cd, VD.z, fmaf(ld, VL.z, BE.z)))));
    rv.w = fmaf(rx, A0.w, fmaf(ry, A1.w, fmaf(rz, A2.w, fmaf(cd, VD.w, fmaf(ld, VL.w, BE.w)))));
    ((float4*)(out + (size_t)row * 128))[q] = rv;
}

extern "C" void kernel_launch(void* const* d_in, const int* in_sizes, int n_in,
                              void* d_out, int out_size, void* d_ws, size_t ws_size,
                              hipStream_t stream) {
    const float* pts    = (const float*)d_in[0];
    const float* W_rel  = (const float*)d_in[1];
    const float* b_rel  = (const float*)d_in[2];
    const float* W_dist = (const float*)d_in[3];
    const float* b_dist = (const float*)d_in[4];
    const float* W_dens = (const float*)d_in[5];
    const float* b_dens = (const float*)d_in[6];
    const float* W_out  = (const float*)d_in[7];
    const float* b_out  = (const float*)d_in[8];
    float* out = (float*)d_out;
    float* ws  = (float*)d_ws;

    hipMemsetAsync(ws + WS_CNT, 0, (size_t)NC * NBATCH * sizeof(int), stream);
    hipLaunchKernelGGL(count_kernel, dim3(32), dim3(1024), 0, stream, pts, ws);
    hipLaunchKernelGGL(prefix_kernel, dim3(NBATCH + 1), dim3(1024), 0, stream,
                       W_rel, b_rel, W_dist, b_dist, W_dens, b_dens, W_out, b_out, ws);
    hipLaunchKernelGGL(scatter_kernel, dim3(32), dim3(1024), 0, stream, pts, ws);
    hipLaunchKernelGGL(knn_kernel, dim3(1024), dim3(256), 0, stream, ws);
    hipLaunchKernelGGL(output_kernel, dim3(4096), dim3(256), 0, stream, pts, ws, out);
}